// Round 9
// baseline (6030.246 us; speedup 1.0000x reference)
//
#include <hip/hip_runtime.h>
#include <hip/hip_bf16.h>

typedef __attribute__((ext_vector_type(8))) short bf8;    // 8 bf16 (4 VGPRs)
typedef __attribute__((ext_vector_type(4))) float f32x4;  // MFMA accumulator
typedef __attribute__((ext_vector_type(4))) unsigned int u32x4;  // asm-safe 128-bit payload

#define T_SEQ 1024

__device__ __forceinline__ float sigm(float x) { return 1.f / (1.f + __expf(-x)); }
__device__ __forceinline__ float tanh_(float x) { return 2.f / (1.f + __expf(-2.f * x)) - 1.f; }

__device__ __forceinline__ short bf16s(float x) {
    union { __hip_bfloat16 h; short s; } u;
    u.h = __float2bfloat16(x);
    return u.s;
}

__device__ __forceinline__ bf8 pack_bf8(const float4 a, const float4 b) {
    bf8 r;
    r[0] = bf16s(a.x); r[1] = bf16s(a.y); r[2] = bf16s(a.z); r[3] = bf16s(a.w);
    r[4] = bf16s(b.x); r[5] = bf16s(b.y); r[6] = bf16s(b.z); r[7] = bf16s(b.w);
    return r;
}

// ---- sc1 (device-scope) access helpers --------------------------------------
// sc1 loads/stores bypass L1 and the non-device-coherent per-XCD L2, meeting at
// the device coherence point (proven cross-XCD-correct, rounds 3-8).
// ROUND-9 PROTOCOL (single change vs r8): producer drains its own data stores
// (s_waitcnt vmcnt(0)) BEFORE the per-wave flag store. r8's post-mortem showed
// the flag systematically led the data without the drain, turning the consumer's
// heavy 2MB retry loop into the de-facto detector (~1-2 extra RTs/step, mostly
// FETCH-invisible because retries hit the MALL). Drain-before-flag = r3's only
// essential ordering guarantee, now at per-wave granularity (no WG coupling).
__device__ __forceinline__ void store_sc1_b32(void* p, unsigned int v) {
    asm volatile("global_store_dword %0, %1, off sc1" :: "v"(p), "v"(v) : "memory");
}
__device__ __forceinline__ unsigned int load_sc1_b32(const void* p) {   // waiting probe
    unsigned int v;
    asm volatile("global_load_dword %0, %1, off sc1\n"
                 "s_waitcnt vmcnt(0)"
                 : "=v"(v) : "v"(p) : "memory");
    return v;
}
__device__ __forceinline__ u32x4 load_sc1_x4(const void* p) {            // no-wait bulk
    u32x4 v;
    asm volatile("global_load_dwordx4 %0, %1, off sc1" : "=v"(v) : "v"(p) : "memory");
    return v;
}

__device__ __forceinline__ unsigned short ldnt_u16(const __hip_bfloat16* p) {
    return __builtin_nontemporal_load((const unsigned short*)p);
}

// ---------------- Phase 0: zero the exchange/flag state (graph-safe) ----------------
// Zeroed exchange = tag 0 + bf16 0.0 everywhere; zeroed flags = "h_0 published".
__global__ __launch_bounds__(256) void init_kernel(unsigned int* __restrict__ p, int n)
{
    const int i = blockIdx.x * 256 + threadIdx.x;
    if (i < n) p[i] = 0u;
}

// ---------------- Phase 1: Xp = bf16(X @ Wih^T + (bih + bhh))  (both directions) ----------------
// X: fp32 [B*T, 512], row m = b*1024 + t.  Wih: fp32 [1024, 512] (B^T layout).
// Xp layout [t][s=16][b=64][g=4][j=16] bf16 (dense per-wave window; verified r5-r8).
__global__ __launch_bounds__(256) void xproj_kernel(
    const float* __restrict__ X,
    const float* __restrict__ WihF,
    const float* __restrict__ bihF,
    const float* __restrict__ bhhF,
    const float* __restrict__ WihB,
    const float* __restrict__ bihB,
    const float* __restrict__ bhhB,
    __hip_bfloat16* __restrict__ XpF,
    __hip_bfloat16* __restrict__ XpB)
{
    const int dir = blockIdx.z;
    const float* W  = dir ? WihB : WihF;
    const float* bi = dir ? bihB : bihF;
    const float* bh = dir ? bhhB : bhhF;
    __hip_bfloat16* Xp = dir ? XpB : XpF;

    __shared__ __align__(16) short As[128 * 32];
    __shared__ __align__(16) short Bs[128 * 32];

    const int tid  = threadIdx.x;
    const int lane = tid & 63;
    const int w    = tid >> 6;
    const int quad = lane >> 4;
    const int l16  = lane & 15;
    const int wr   = w >> 1, wc = w & 1;      // 2x2 wave grid, 64x64 per wave

    const int m0 = blockIdx.x * 128;
    const int n0 = blockIdx.y * 128;

    const int srow = tid >> 2;                // staging row within 64-row half
    const int scg  = tid & 3;                 // 8-col group

    f32x4 acc[4][4] = {};

    for (int kk = 0; kk < 512; kk += 32) {
        const float* pa0 = X + (size_t)(m0 + srow)      * 512 + kk + scg * 8;
        const float* pa1 = X + (size_t)(m0 + 64 + srow) * 512 + kk + scg * 8;
        const float* pb0 = W + (size_t)(n0 + srow)      * 512 + kk + scg * 8;
        const float* pb1 = W + (size_t)(n0 + 64 + srow) * 512 + kk + scg * 8;
        bf8 a0 = pack_bf8(*(const float4*)pa0, *(const float4*)(pa0 + 4));
        bf8 a1 = pack_bf8(*(const float4*)pa1, *(const float4*)(pa1 + 4));
        bf8 b0 = pack_bf8(*(const float4*)pb0, *(const float4*)(pb0 + 4));
        bf8 b1 = pack_bf8(*(const float4*)pb1, *(const float4*)(pb1 + 4));
        __syncthreads();  // previous iteration's LDS reads done
        *(bf8*)&As[(srow)      * 32 + scg * 8] = a0;
        *(bf8*)&As[(64 + srow) * 32 + scg * 8] = a1;
        *(bf8*)&Bs[(srow)      * 32 + scg * 8] = b0;
        *(bf8*)&Bs[(64 + srow) * 32 + scg * 8] = b1;
        __syncthreads();

        bf8 af[4], bfr[4];
#pragma unroll
        for (int mt = 0; mt < 4; mt++)
            af[mt] = *(const bf8*)&As[(wr * 64 + mt * 16 + l16) * 32 + quad * 8];
#pragma unroll
        for (int nt = 0; nt < 4; nt++)
            bfr[nt] = *(const bf8*)&Bs[(wc * 64 + nt * 16 + l16) * 32 + quad * 8];
#pragma unroll
        for (int mt = 0; mt < 4; mt++)
#pragma unroll
            for (int nt = 0; nt < 4; nt++)
                acc[mt][nt] = __builtin_amdgcn_mfma_f32_16x16x32_bf16(af[mt], bfr[nt], acc[mt][nt], 0, 0, 0);
    }

#pragma unroll
    for (int nt = 0; nt < 4; nt++) {
        const int n = n0 + wc * 64 + nt * 16 + l16;   // j == l16 (all tile offsets are x16)
        const float bias = bi[n] + bh[n];
        const int g = n >> 8, s = (n >> 4) & 15, j = n & 15;
#pragma unroll
        for (int mt = 0; mt < 4; mt++) {
#pragma unroll
            for (int r = 0; r < 4; r++) {
                const int m = m0 + wr * 64 + mt * 16 + quad * 4 + r;   // C/D: row=quad*4+r, col=l16
                const int b = m >> 10, t = m & 1023;                    // m = b*1024 + t
                Xp[((((size_t)t * 16 + s) * 64 + b) * 4 + g) * 16 + j] =
                    __float2bfloat16(acc[mt][nt][r] + bias);
            }
        }
    }
}

// ---------------- Phase 2: recurrence — per-wave drain-then-flag protocol. ----------------
// 32 WGs = 128 independent WAVES (dir, slice s, batch-tile w); no barriers, no LDS.
// Exchange EX[buf=2][dir=2][slice=16][b=64][j=16] dwords, dword=(tag<<16)|bf16(h),
// tag = step index (h_tau tagged tau; verified r4-r8).
// Producer wave: 4 tagged sc1 data stores -> s_waitcnt vmcnt(0) DRAIN -> lane0
// sc1 per-wave flag store -> out stores. Flag now GUARANTEES data visibility
// (r3's essential ordering, per-wave granularity) -> consumer never retries.
// Consumer wave: light flag spin (lane L polls flags[dir][L&15][w]) -> Xp loads
// + bulk Af loads together under ONE vmcnt (Xp's ~900cy HBM hides under the
// ~2k-cy exchange RT) -> tag validation (safety net; bounded retry should never
// trigger). Anti-overwrite closes per (dir,w) group (verified r6 argument).
__global__ __launch_bounds__(256, 1) void lstm_rec_kernel(
    const __hip_bfloat16* __restrict__ XpF,
    const __hip_bfloat16* __restrict__ XpB,
    const float* __restrict__ WhhF,
    const float* __restrict__ WhhB,
    unsigned int* __restrict__ ex,
    unsigned int* __restrict__ flags,   // [dir=2][s=16][w=4], 32 B spacing
    float* __restrict__ out)
{
    const int wg  = blockIdx.x;
    const int dir = wg >> 4;
    const int s   = wg & 15;
    const int tid  = threadIdx.x;
    const int lane = tid & 63;
    const int w    = tid >> 6;       // wave = batch tile (16 batches)
    const int quad = lane >> 4;
    const int l16  = lane & 15;

    const __hip_bfloat16* Xp = dir ? XpB : XpF;
    const float* Whh         = dir ? WhhB : WhhF;

    // Preload Whh slice into registers: Bf[gate][kstep], B-frag layout n=l16, k=quad*8+j.
    bf8 Bf[4][8];
#pragma unroll
    for (int g = 0; g < 4; g++)
#pragma unroll
        for (int k = 0; k < 8; k++) {
            const float* p = Whh + (size_t)(g * 256 + s * 16 + l16) * 256 + k * 32 + quad * 8;
            Bf[g][k] = pack_bf8(*(const float4*)p, *(const float4*)(p + 4));
        }

    float c[4] = {0.f, 0.f, 0.f, 0.f};   // cell state, fp32, never rounded

    // Consumer A-frag addressing (verified r4-r8): frag k8 reads slice row
    // (k8*2 + crow) at dword offset coff; A layout m=l16, k=quad*8+j.
    const int crow = quad >> 1;
    const int coff = (w * 16 + l16) * 16 + (quad & 1) * 8;
    unsigned int* const exdir = ex + (dir << 14);
    unsigned int* const myflag   = flags + ((dir * 16 + s) * 4 + w) * 8;            // producer
    const unsigned int* pollflag = flags + ((dir * 16 + (lane & 15)) * 4 + w) * 8;  // consumer

    for (int tau = 0; tau < T_SEQ; tau++) {
        const int t = dir ? (T_SEQ - 1 - tau) : tau;
        const unsigned int tagv = (unsigned int)tau;
        const unsigned int tagw = tagv << 16;
        unsigned int* const exc = exdir + ((tau & 1) << 15);

        // ---- light spin on per-wave flags (flag => data visible, no retries) ----
        {
            int guard = 0;
            while (true) {
                const unsigned int fv = load_sc1_b32(pollflag);
                if (__all((int)(fv >= tagv))) break;
                if (++guard >= 8192) break;   // fail-fast into verification, never hang
            }
        }

        // ---- Xp + bulk Af together under one vmcnt (Xp HBM hides under exchange RT) ----
        const __hip_bfloat16* xrow = Xp + ((((size_t)t * 16 + s) * 64 + w * 16) * 4) * 16;
        unsigned short xpu[4][4];
#pragma unroll
        for (int g = 0; g < 4; g++)
#pragma unroll
            for (int r = 0; r < 4; r++)
                xpu[g][r] = ldnt_u16(&xrow[((quad * 4 + r) * 4 + g) * 16 + l16]);

        u32x4 dd[16];
#pragma unroll
        for (int k8 = 0; k8 < 8; k8++) {
            dd[2 * k8]     = load_sc1_x4(exc + (k8 * 2 + crow) * 1024 + coff);
            dd[2 * k8 + 1] = load_sc1_x4(exc + (k8 * 2 + crow) * 1024 + coff + 4);
        }
        asm volatile("s_waitcnt vmcnt(0)" ::: "memory");
        __builtin_amdgcn_sched_barrier(0);   // rule 18: keep checks below the waitcnt

        // ---- tag validation: pure safety net (drain-before-flag => should never loop) ----
        {
            unsigned int diff = 0;
#pragma unroll
            for (int i = 0; i < 16; i++) {
                diff |= (dd[i][0] ^ tagw) & 0xFFFF0000u;
                diff |= (dd[i][1] ^ tagw) & 0xFFFF0000u;
                diff |= (dd[i][2] ^ tagw) & 0xFFFF0000u;
                diff |= (dd[i][3] ^ tagw) & 0xFFFF0000u;
            }
            int bguard = 0;
            while (!__all((int)(diff == 0u)) && ++bguard < 256) {
#pragma unroll
                for (int k8 = 0; k8 < 8; k8++) {
                    dd[2 * k8]     = load_sc1_x4(exc + (k8 * 2 + crow) * 1024 + coff);
                    dd[2 * k8 + 1] = load_sc1_x4(exc + (k8 * 2 + crow) * 1024 + coff + 4);
                }
                asm volatile("s_waitcnt vmcnt(0)" ::: "memory");
                __builtin_amdgcn_sched_barrier(0);
                diff = 0;
#pragma unroll
                for (int i = 0; i < 16; i++) {
                    diff |= (dd[i][0] ^ tagw) & 0xFFFF0000u;
                    diff |= (dd[i][1] ^ tagw) & 0xFFFF0000u;
                    diff |= (dd[i][2] ^ tagw) & 0xFFFF0000u;
                    diff |= (dd[i][3] ^ tagw) & 0xFFFF0000u;
                }
            }
        }

        // ---- MFMA: unpack each A-frag just before its 4 MFMAs ----
        f32x4 acc[4];
        const f32x4 zero = {0.f, 0.f, 0.f, 0.f};
#pragma unroll
        for (int g = 0; g < 4; g++) acc[g] = zero;
#pragma unroll
        for (int k8 = 0; k8 < 8; k8++) {
            bf8 Af;
#pragma unroll
            for (int j = 0; j < 4; j++) {
                Af[j]     = (short)(dd[2 * k8][j]     & 0xFFFFu);
                Af[4 + j] = (short)(dd[2 * k8 + 1][j] & 0xFFFFu);
            }
#pragma unroll
            for (int g = 0; g < 4; g++)
                acc[g] = __builtin_amdgcn_mfma_f32_16x16x32_bf16(Af, Bf[g][k8], acc[g], 0, 0, 0);
        }

        // ---- gates -> tagged publish -> DRAIN -> per-wave flag -> out stores ----
        const unsigned int pubtag = (unsigned int)(tau + 1) << 16;
        unsigned int* const dst = exdir + (((tau + 1) & 1) << 15) + (s << 10);
        float hv[4];
#pragma unroll
        for (int r = 0; r < 4; r++) {
            union { unsigned int u; float f; } cv0, cv1, cv2, cv3;
            cv0.u = (unsigned int)xpu[0][r] << 16;
            cv1.u = (unsigned int)xpu[1][r] << 16;
            cv2.u = (unsigned int)xpu[2][r] << 16;
            cv3.u = (unsigned int)xpu[3][r] << 16;
            const float ig = sigm(acc[0][r] + cv0.f);
            const float fg = sigm(acc[1][r] + cv1.f);
            const float gg = tanh_(acc[2][r] + cv2.f);
            const float og = sigm(acc[3][r] + cv3.f);
            c[r] = fg * c[r] + ig * gg;
            hv[r] = og * tanh_(c[r]);
            const int b = w * 16 + quad * 4 + r;
            store_sc1_b32(&dst[b * 16 + l16],
                          pubtag | (unsigned int)(unsigned short)bf16s(hv[r]));
        }
        // THE round-9 change: drain own data stores so the flag implies visibility.
        asm volatile("s_waitcnt vmcnt(0)" ::: "memory");
        if (lane == 0) store_sc1_b32(myflag, (unsigned int)(tau + 1));

        // Output stores after the flag (their drain overlaps the next spin).
#pragma unroll
        for (int r = 0; r < 4; r++) {
            const int b = w * 16 + quad * 4 + r;
            __builtin_nontemporal_store(hv[r], &out[((size_t)b * T_SEQ + t) * 512 + dir * 256 + s * 16 + l16]);
        }
    }
}

extern "C" void kernel_launch(void* const* d_in, const int* in_sizes, int n_in,
                              void* d_out, int out_size, void* d_ws, size_t ws_size,
                              hipStream_t stream)
{
    const float* X    = (const float*)d_in[0];
    const float* WihF = (const float*)d_in[1];
    const float* WhhF = (const float*)d_in[2];
    const float* bihF = (const float*)d_in[3];
    const float* bhhF = (const float*)d_in[4];
    const float* WihB = (const float*)d_in[5];
    const float* WhhB = (const float*)d_in[6];
    const float* bihB = (const float*)d_in[7];
    const float* bhhB = (const float*)d_in[8];
    float* out = (float*)d_out;

    char* ws = (char*)d_ws;
    __hip_bfloat16* XpF   = (__hip_bfloat16*)ws;                       // 128 MB
    __hip_bfloat16* XpB   = (__hip_bfloat16*)(ws + 134217728);         // 128 MB
    unsigned int*   ex    = (unsigned int*)(ws + 268435456);           // 256 KB tagged exchange
    unsigned int*   flags = (unsigned int*)(ws + 268435456 + 262144);  // 16 KB per-wave flags

    // Zero exchange + flags each replay: tag 0 + 0.0 == "h_0 ready"; flag 0 == published.
    const int initN = (262144 + 16384) / 4;
    init_kernel<<<(initN + 255) / 256, 256, 0, stream>>>(ex, initN);

    dim3 g1(512, 8, 2);   // 65536/128 m-tiles, 1024/128 n-tiles, 2 directions
    xproj_kernel<<<g1, 256, 0, stream>>>(X, WihF, bihF, bhhF, WihB, bihB, bhhB, XpF, XpB);
    lstm_rec_kernel<<<32, 256, 0, stream>>>(XpF, XpB, WhhF, WhhB, ex, flags, out);
}

// Round 10
// 4399.516 us; speedup vs baseline: 1.3707x; 1.3707x over previous
//
#include <hip/hip_runtime.h>
#include <hip/hip_bf16.h>

typedef __attribute__((ext_vector_type(8))) short bf8;    // 8 bf16 (4 VGPRs)
typedef __attribute__((ext_vector_type(4))) float f32x4;  // MFMA accumulator
typedef __attribute__((ext_vector_type(2))) unsigned int u32x2;  // asm-safe 64-bit payload

#define T_SEQ 1024

__device__ __forceinline__ float sigm(float x) { return 1.f / (1.f + __expf(-x)); }
__device__ __forceinline__ float tanh_(float x) { return 2.f / (1.f + __expf(-2.f * x)) - 1.f; }

__device__ __forceinline__ short bf16s(float x) {
    union { __hip_bfloat16 h; short s; } u;
    u.h = __float2bfloat16(x);
    return u.s;
}

__device__ __forceinline__ bf8 pack_bf8(const float4 a, const float4 b) {
    bf8 r;
    r[0] = bf16s(a.x); r[1] = bf16s(a.y); r[2] = bf16s(a.z); r[3] = bf16s(a.w);
    r[4] = bf16s(b.x); r[5] = bf16s(b.y); r[6] = bf16s(b.z); r[7] = bf16s(b.w);
    return r;
}

// ---- sc1 (device-scope, LLC-coherent) access helpers -----------------------
// sc1 = device scope: loads bypass L1 and the non-device-coherent per-XCD L2,
// reading the coherence point; stores write through to it. Proven cross-XCD
// correct on this problem (rounds 3-9). This is the round-3 protocol — the
// measured best of seven variants (3812 us rec vs 4310-7035 for the others):
//   publish: sc1 dwordx2 stores -> per-wave vmcnt(0) drain -> barrier -> tid0
//            sc1 flag store (flag GUARANTEES data visibility; no retries ever)
//   consume: 16 lanes of wave 0 hard-poll sc1 flags -> barrier -> sc1 Af bulk
// Per-step chain ~4 LLC round trips + compute; measured floor for any
// poll-based scheme is ~3 RT + compute, so this sits ~25% above the floor.
// Variants that tried to remove hops (fire-and-forget tags r4-r6, per-wave
// flags r8/r9, dual-direction r7) all measured slower — detection cost moved,
// it never disappeared.
__device__ __forceinline__ void store_sc1_b64(void* p, unsigned int lo, unsigned int hi) {
    u32x2 v; v[0] = lo; v[1] = hi;
    asm volatile("global_store_dwordx2 %0, %1, off sc1" :: "v"(p), "v"(v) : "memory");
}
__device__ __forceinline__ void store_sc1_b32(void* p, unsigned int v) {
    asm volatile("global_store_dword %0, %1, off sc1" :: "v"(p), "v"(v) : "memory");
}
__device__ __forceinline__ unsigned int load_sc1_b32(const void* p) {
    unsigned int v;
    asm volatile("global_load_dword %0, %1, off sc1\n"
                 "s_waitcnt vmcnt(0)"
                 : "=v"(v) : "v"(p) : "memory");
    return v;
}
__device__ __forceinline__ bf8 load_sc1_b128(const void* p) {
    bf8 v;  // issued without waitcnt so the 8 frag loads pipeline
    asm volatile("global_load_dwordx4 %0, %1, off sc1" : "=v"(v) : "v"(p) : "memory");
    return v;
}

// ---------------- Phase 0: zero the exchange/flag state (graph-safe) ----------------
__global__ __launch_bounds__(256) void init_kernel(unsigned int* __restrict__ p, int n)
{
    const int i = blockIdx.x * 256 + threadIdx.x;
    if (i < n) p[i] = 0u;
}

// ---------------- Phase 1: Xp = bf16(X @ Wih^T + (bih + bhh))  (both directions) ----------------
// X: fp32 [B*T, 512], row m = b*1024 + t.  Wih: fp32 [1024, 512] (B^T layout).
// Xp: bf16 stored [t][b][1024] -> row (t*64 + b).   (verified round 3)
__global__ __launch_bounds__(256) void xproj_kernel(
    const float* __restrict__ X,
    const float* __restrict__ WihF,
    const float* __restrict__ bihF,
    const float* __restrict__ bhhF,
    const float* __restrict__ WihB,
    const float* __restrict__ bihB,
    const float* __restrict__ bhhB,
    __hip_bfloat16* __restrict__ XpF,
    __hip_bfloat16* __restrict__ XpB)
{
    const int dir = blockIdx.z;
    const float* W  = dir ? WihB : WihF;
    const float* bi = dir ? bihB : bihF;
    const float* bh = dir ? bhhB : bhhF;
    __hip_bfloat16* Xp = dir ? XpB : XpF;

    __shared__ __align__(16) short As[128 * 32];
    __shared__ __align__(16) short Bs[128 * 32];

    const int tid  = threadIdx.x;
    const int lane = tid & 63;
    const int w    = tid >> 6;
    const int quad = lane >> 4;
    const int l16  = lane & 15;
    const int wr   = w >> 1, wc = w & 1;      // 2x2 wave grid, 64x64 per wave

    const int m0 = blockIdx.x * 128;
    const int n0 = blockIdx.y * 128;

    const int srow = tid >> 2;                // staging row within 64-row half
    const int scg  = tid & 3;                 // 8-col group

    f32x4 acc[4][4] = {};

    for (int kk = 0; kk < 512; kk += 32) {
        const float* pa0 = X + (size_t)(m0 + srow)      * 512 + kk + scg * 8;
        const float* pa1 = X + (size_t)(m0 + 64 + srow) * 512 + kk + scg * 8;
        const float* pb0 = W + (size_t)(n0 + srow)      * 512 + kk + scg * 8;
        const float* pb1 = W + (size_t)(n0 + 64 + srow) * 512 + kk + scg * 8;
        bf8 a0 = pack_bf8(*(const float4*)pa0, *(const float4*)(pa0 + 4));
        bf8 a1 = pack_bf8(*(const float4*)pa1, *(const float4*)(pa1 + 4));
        bf8 b0 = pack_bf8(*(const float4*)pb0, *(const float4*)(pb0 + 4));
        bf8 b1 = pack_bf8(*(const float4*)pb1, *(const float4*)(pb1 + 4));
        __syncthreads();  // previous iteration's LDS reads done
        *(bf8*)&As[(srow)      * 32 + scg * 8] = a0;
        *(bf8*)&As[(64 + srow) * 32 + scg * 8] = a1;
        *(bf8*)&Bs[(srow)      * 32 + scg * 8] = b0;
        *(bf8*)&Bs[(64 + srow) * 32 + scg * 8] = b1;
        __syncthreads();

        bf8 af[4], bfr[4];
#pragma unroll
        for (int mt = 0; mt < 4; mt++)
            af[mt] = *(const bf8*)&As[(wr * 64 + mt * 16 + l16) * 32 + quad * 8];
#pragma unroll
        for (int nt = 0; nt < 4; nt++)
            bfr[nt] = *(const bf8*)&Bs[(wc * 64 + nt * 16 + l16) * 32 + quad * 8];
#pragma unroll
        for (int mt = 0; mt < 4; mt++)
#pragma unroll
            for (int nt = 0; nt < 4; nt++)
                acc[mt][nt] = __builtin_amdgcn_mfma_f32_16x16x32_bf16(af[mt], bfr[nt], acc[mt][nt], 0, 0, 0);
    }

#pragma unroll
    for (int nt = 0; nt < 4; nt++) {
        const int n = n0 + wc * 64 + nt * 16 + l16;
        const float bias = bi[n] + bh[n];
#pragma unroll
        for (int mt = 0; mt < 4; mt++) {
#pragma unroll
            for (int r = 0; r < 4; r++) {
                const int m = m0 + wr * 64 + mt * 16 + quad * 4 + r;   // C/D: row=quad*4+r, col=l16
                const int b = m >> 10, t = m & 1023;                    // m = b*1024 + t
                Xp[((size_t)t * 64 + b) * 1024 + n] = __float2bfloat16(acc[mt][nt][r] + bias);
            }
        }
    }
}

// ---------------- Phase 2: recurrence. 32 persistent WGs (16 per direction). ----------------
// WG (dir, s) owns hidden units j = s*16 .. s*16+15 (gate rows g*256 + s*16 + j), all 64 batches.
// Whh slice in registers. h exchanged via hexch in the LLC, double-buffered:
// hexch[buf][dir][slice][64][16] bf16.
// Exchange protocol (all relaxed sc1 = device scope, LLC coherence point; no wbl2/inv):
//   publish: sc1 dwordx2 stores -> per-wave vmcnt(0) drain -> barrier -> tid0 sc1 flag store
//   consume: 16 lanes of wave 0 hard-poll sc1 (no sleep) -> barrier -> sc1 Af loads
__global__ __launch_bounds__(256, 1) void lstm_rec_kernel(
    const __hip_bfloat16* __restrict__ XpF,
    const __hip_bfloat16* __restrict__ XpB,
    const float* __restrict__ WhhF,
    const float* __restrict__ WhhB,
    __hip_bfloat16* __restrict__ hexch,
    int* __restrict__ flags,
    float* __restrict__ out)
{
    const int wg  = blockIdx.x;
    const int dir = wg >> 4;
    const int s   = wg & 15;
    const int tid  = threadIdx.x;
    const int lane = tid & 63;
    const int w    = tid >> 6;       // wave = batch tile (16 batches)
    const int quad = lane >> 4;
    const int l16  = lane & 15;

    const __hip_bfloat16* Xp = dir ? XpB : XpF;
    const float* Whh         = dir ? WhhB : WhhF;
    unsigned int* hexchU     = (unsigned int*)hexch;

    __shared__ unsigned int hstage[512];   // [64 b][16 j] bf16 = 2 KB, dword view

    // Preload Whh slice into registers: Bf[gate][kstep], B-frag layout n=l16, k=quad*8+j.
    bf8 Bf[4][8];
#pragma unroll
    for (int g = 0; g < 4; g++)
#pragma unroll
        for (int k = 0; k < 8; k++) {
            const float* p = Whh + (size_t)(g * 256 + s * 16 + l16) * 256 + k * 32 + quad * 8;
            Bf[g][k] = pack_bf8(*(const float4*)p, *(const float4*)(p + 4));
        }

    float c[4] = {0.f, 0.f, 0.f, 0.f};   // cell state, fp32, never rounded

    // h_0 = 0 and flags = 0 ("h_0 ready") are established by init_kernel (its dirty
    // lines are written back to LLC at its end-of-dispatch release; our sc1 accesses
    // read the LLC directly).

    for (int tau = 0; tau < T_SEQ; tau++) {
        const int t = dir ? (T_SEQ - 1 - tau) : tau;

        // Spin: 16 lanes of wave 0, one flag each (128 B apart), sc1 hard poll.
        // xp loads are issued AFTER the spin so the probe's vmcnt(0) only drains the
        // previous step's 4 out-stores, not 16 in-flight loads.
        if (tid < 16) {
            int* f = &flags[(dir * 16 + tid) * 32];
            while ((int)load_sc1_b32(f) < tau) { }
        }
        __syncthreads();

        // Xp loads (raw bf16 bits; converted and accumulated after the MFMAs).
        unsigned short xpu[4][4];
#pragma unroll
        for (int g = 0; g < 4; g++)
#pragma unroll
            for (int r = 0; r < 4; r++) {
                const int b = w * 16 + quad * 4 + r;
                xpu[g][r] = __builtin_nontemporal_load(
                    (const unsigned short*)&Xp[((size_t)t * 64 + b) * 1024 + g * 256 + s * 16 + l16]);
            }

        // A-frags (h_tau) from hexch buf tau&1: sc1 loads read the LLC directly —
        // no stale L1/L2 possible, so no acquire fence / cache invalidate needed.
        const __hip_bfloat16* hb = hexch + ((size_t)((tau & 1) * 2 + dir) * 16) * 1024;
        bf8 Af[8];
#pragma unroll
        for (int k = 0; k < 8; k++) {
            const int sA = k * 2 + (quad >> 1);          // slice holding k-cols [k*32+quad*8, +8)
            Af[k] = load_sc1_b128(hb + (size_t)sA * 1024 + (w * 16 + l16) * 16 + (quad & 1) * 8);
        }
        asm volatile("s_waitcnt vmcnt(0)" ::: "memory");
        __builtin_amdgcn_sched_barrier(0);   // rule 18: keep MFMAs below the asm waitcnt

        f32x4 acc[4];
        const f32x4 zero = {0.f, 0.f, 0.f, 0.f};
#pragma unroll
        for (int g = 0; g < 4; g++) acc[g] = zero;
#pragma unroll
        for (int k = 0; k < 8; k++)
#pragma unroll
            for (int g = 0; g < 4; g++)
                acc[g] = __builtin_amdgcn_mfma_f32_16x16x32_bf16(Af[k], Bf[g][k], acc[g], 0, 0, 0);

        // Gates; lane holds i,f,g,o for (b = w*16+quad*4+r, j = s*16+l16).
        // xp (Wih*x + bias) is added here, after the recurrent MFMAs.
        float hv[4];
#pragma unroll
        for (int r = 0; r < 4; r++) {
            union { unsigned int u; float f; } cv0, cv1, cv2, cv3;
            cv0.u = (unsigned int)xpu[0][r] << 16;
            cv1.u = (unsigned int)xpu[1][r] << 16;
            cv2.u = (unsigned int)xpu[2][r] << 16;
            cv3.u = (unsigned int)xpu[3][r] << 16;
            const float ig = sigm(acc[0][r] + cv0.f);
            const float fg = sigm(acc[1][r] + cv1.f);
            const float gg = tanh_(acc[2][r] + cv2.f);
            const float og = sigm(acc[3][r] + cv3.f);
            c[r] = fg * c[r] + ig * gg;
            hv[r] = og * tanh_(c[r]);
            const int b = w * 16 + quad * 4 + r;
            ((__hip_bfloat16*)hstage)[b * 16 + l16] = __float2bfloat16(hv[r]);
        }
        __syncthreads();   // hstage complete

        // Publish h_{tau+1}: sc1 write-through dwordx2 per thread into the LLC.
        {
            unsigned int* dst = hexchU + ((size_t)(((tau + 1) & 1) * 2 + dir) * 16 + s) * 512;
            store_sc1_b64(&dst[2 * tid], hstage[2 * tid], hstage[2 * tid + 1]);
        }
        asm volatile("s_waitcnt vmcnt(0)" ::: "memory");   // per-wave drain: data is in LLC
        __syncthreads();                                    // all waves drained
        if (tid == 0)
            store_sc1_b32(&flags[(dir * 16 + s) * 32], (unsigned int)(tau + 1));

        // Output stores off the critical path (drain overlaps next spin).
#pragma unroll
        for (int r = 0; r < 4; r++) {
            const int b = w * 16 + quad * 4 + r;
            __builtin_nontemporal_store(hv[r], &out[((size_t)b * T_SEQ + t) * 512 + dir * 256 + s * 16 + l16]);
        }
    }
}

extern "C" void kernel_launch(void* const* d_in, const int* in_sizes, int n_in,
                              void* d_out, int out_size, void* d_ws, size_t ws_size,
                              hipStream_t stream)
{
    const float* X    = (const float*)d_in[0];
    const float* WihF = (const float*)d_in[1];
    const float* WhhF = (const float*)d_in[2];
    const float* bihF = (const float*)d_in[3];
    const float* bhhF = (const float*)d_in[4];
    const float* WihB = (const float*)d_in[5];
    const float* WhhB = (const float*)d_in[6];
    const float* bihB = (const float*)d_in[7];
    const float* bhhB = (const float*)d_in[8];
    float* out = (float*)d_out;

    char* ws = (char*)d_ws;
    __hip_bfloat16* XpF   = (__hip_bfloat16*)ws;                           // 128 MB
    __hip_bfloat16* XpB   = (__hip_bfloat16*)(ws + 134217728);             // 128 MB
    __hip_bfloat16* hexch = (__hip_bfloat16*)(ws + 268435456);             // 128 KB
    int*            flags = (int*)(ws + 268435456 + 131072);               // 4 KB (128 B spacing)

    // Zero h_0 buffers and flags (0 == "h_0 ready") each replay.
    // Plain kernel (graph-capture-safe; no hipMemset* inside kernel_launch).
    const int initN = (131072 + 4096) / 4;
    init_kernel<<<(initN + 255) / 256, 256, 0, stream>>>((unsigned int*)(ws + 268435456), initN);

    dim3 g1(512, 8, 2);   // 65536/128 m-tiles, 1024/128 n-tiles, 2 directions
    xproj_kernel<<<g1, 256, 0, stream>>>(X, WihF, bihF, bhhF, WihB, bihB, bhhB, XpF, XpB);
    lstm_rec_kernel<<<32, 256, 0, stream>>>(XpF, XpB, WhhF, WhhB, hexch, flags, out);
}

// Round 11
// 4160.513 us; speedup vs baseline: 1.4494x; 1.0574x over previous
//
#include <hip/hip_runtime.h>
#include <hip/hip_bf16.h>

typedef __attribute__((ext_vector_type(8))) short bf8;    // 8 bf16 (4 VGPRs)
typedef __attribute__((ext_vector_type(4))) float f32x4;  // MFMA accumulator
typedef __attribute__((ext_vector_type(2))) unsigned int u32x2;  // asm-safe 64-bit payload

#define T_SEQ 1024

__device__ __forceinline__ float sigm(float x) { return 1.f / (1.f + __expf(-x)); }
__device__ __forceinline__ float tanh_(float x) { return 2.f / (1.f + __expf(-2.f * x)) - 1.f; }

__device__ __forceinline__ short bf16s(float x) {
    union { __hip_bfloat16 h; short s; } u;
    u.h = __float2bfloat16(x);
    return u.s;
}

__device__ __forceinline__ bf8 pack_bf8(const float4 a, const float4 b) {
    bf8 r;
    r[0] = bf16s(a.x); r[1] = bf16s(a.y); r[2] = bf16s(a.z); r[3] = bf16s(a.w);
    r[4] = bf16s(b.x); r[5] = bf16s(b.y); r[6] = bf16s(b.z); r[7] = bf16s(b.w);
    return r;
}

// ---- sc1 (device-scope, LLC-coherent) access helpers -----------------------
// sc1 = device scope: loads bypass L1 and the non-device-coherent per-XCD L2,
// reading the coherence point; stores write through to it. Proven cross-XCD
// correct on this problem (rounds 3-10). The h-exchange protocol below is the
// measured best of seven variants (r3/r10, ~3.9 ms rec):
//   publish: sc1 stores -> per-wave vmcnt(0) drain -> barrier -> tid0 sc1 flag
//   consume: 16 lanes of wave 0 hard-poll sc1 flags -> barrier -> sc1 bulk
// NEW this round: xproj is FUSED into the same dispatch and overlapped with the
// recurrence. Xp visibility uses the SAME drain-then-signal machinery: sc1
// write-through Xp stores -> vmcnt(0) -> barrier -> device-scope atomicAdd on a
// per-(dir,chunk) counter; rec gates on counter==512 once per 128 steps.
__device__ __forceinline__ void store_sc1_b64(void* p, unsigned int lo, unsigned int hi) {
    u32x2 v; v[0] = lo; v[1] = hi;
    asm volatile("global_store_dwordx2 %0, %1, off sc1" :: "v"(p), "v"(v) : "memory");
}
__device__ __forceinline__ void store_sc1_b32(void* p, unsigned int v) {
    asm volatile("global_store_dword %0, %1, off sc1" :: "v"(p), "v"(v) : "memory");
}
__device__ __forceinline__ void store_sc1_b16(void* p, unsigned short v) {
    unsigned int vv = v;
    asm volatile("global_store_short %0, %1, off sc1" :: "v"(p), "v"(vv) : "memory");
}
__device__ __forceinline__ unsigned int load_sc1_b32(const void* p) {
    unsigned int v;
    asm volatile("global_load_dword %0, %1, off sc1\n"
                 "s_waitcnt vmcnt(0)"
                 : "=v"(v) : "v"(p) : "memory");
    return v;
}
__device__ __forceinline__ bf8 load_sc1_b128(const void* p) {
    bf8 v;  // issued without waitcnt so the 8 frag loads pipeline
    asm volatile("global_load_dwordx4 %0, %1, off sc1" : "=v"(v) : "v"(p) : "memory");
    return v;
}

// ---------------- Phase 0: zero exchange/flag/counter state (graph-safe) ----------------
__global__ __launch_bounds__(256) void init_kernel(unsigned int* __restrict__ p, int n)
{
    const int i = blockIdx.x * 256 + threadIdx.x;
    if (i < n) p[i] = 0u;
}

// ---------------- Fused kernel: rec (blocks 0..31) + xproj (blocks 32..8223) ----------------
// xproj block order is stage-major: stage s in [0,8) covers (fwd chunk s) and
// (bwd chunk 7-s) for all 64 batches x 8 n-tiles — both directions' consumption
// order. Deadlock-free in ANY dispatch order: xproj never waits; rec waits only
// on monotonic counters that xproj unconditionally reaches; worst case (rec
// dispatched last / adversarial order) degrades to the serial anchor (~4.4 ms).
__global__ __launch_bounds__(256, 1) void fused_kernel(
    const float* __restrict__ X,
    const float* __restrict__ WihF,
    const float* __restrict__ bihF,
    const float* __restrict__ bhhF,
    const float* __restrict__ WihB,
    const float* __restrict__ bihB,
    const float* __restrict__ bhhB,
    const float* __restrict__ WhhF,
    const float* __restrict__ WhhB,
    __hip_bfloat16* __restrict__ XpF,
    __hip_bfloat16* __restrict__ XpB,
    __hip_bfloat16* __restrict__ hexch,
    int* __restrict__ flags,
    int* __restrict__ cnt,        // [dir=2][chunk=8] completion counters (target 512)
    float* __restrict__ out)
{
    __shared__ __align__(16) unsigned char smem[16384];   // xproj: As|Bs; rec: hstage
    const int tid  = threadIdx.x;
    const int lane = tid & 63;
    const int quad = lane >> 4;
    const int l16  = lane & 15;

    if (blockIdx.x < 32) {
        // ================= REC body (r10 verbatim + per-chunk Xp gate) =================
        const int wg  = blockIdx.x;
        const int dir = wg >> 4;
        const int s   = wg & 15;
        const int w   = tid >> 6;       // wave = batch tile (16 batches)

        const __hip_bfloat16* Xp = dir ? XpB : XpF;
        const float* Whh         = dir ? WhhB : WhhF;
        unsigned int* hexchU     = (unsigned int*)hexch;
        unsigned int* hstage     = (unsigned int*)smem;   // [64 b][16 j] bf16 = 2 KB

        // Preload Whh slice: Bf[gate][kstep], B-frag layout n=l16, k=quad*8+j.
        bf8 Bf[4][8];
#pragma unroll
        for (int g = 0; g < 4; g++)
#pragma unroll
            for (int k = 0; k < 8; k++) {
                const float* p = Whh + (size_t)(g * 256 + s * 16 + l16) * 256 + k * 32 + quad * 8;
                Bf[g][k] = pack_bf8(*(const float4*)p, *(const float4*)(p + 4));
            }

        float c[4] = {0.f, 0.f, 0.f, 0.f};   // cell state, fp32, never rounded

        for (int tau = 0; tau < T_SEQ; tau++) {
            const int t = dir ? (T_SEQ - 1 - tau) : tau;

            // Gate on Xp chunk readiness (once per 128 steps; counter at LLC).
            if ((tau & 127) == 0) {
                if (tid == 0) {
                    const int chunk = dir ? (7 - (tau >> 7)) : (tau >> 7);
                    const int* cp = &cnt[dir * 8 + chunk];
                    int guard = 0;
                    while ((int)load_sc1_b32(cp) < 512 && ++guard < (1 << 20)) { }
                }
                __syncthreads();
            }

            // Spin: 16 lanes of wave 0, one h-flag each (128 B apart), sc1 hard poll.
            if (tid < 16) {
                int* f = &flags[(dir * 16 + tid) * 32];
                while ((int)load_sc1_b32(f) < tau) { }
            }
            __syncthreads();

            // Xp loads (raw bf16 bits; accumulated after the MFMAs). Fresh from LLC:
            // producer wrote them sc1 write-through; NT loads don't hit stale L1/L2.
            unsigned short xpu[4][4];
#pragma unroll
            for (int g = 0; g < 4; g++)
#pragma unroll
                for (int r = 0; r < 4; r++) {
                    const int b = w * 16 + quad * 4 + r;
                    xpu[g][r] = __builtin_nontemporal_load(
                        (const unsigned short*)&Xp[((size_t)t * 64 + b) * 1024 + g * 256 + s * 16 + l16]);
                }

            // A-frags (h_tau) from hexch buf tau&1: sc1 loads read the LLC directly.
            const __hip_bfloat16* hb = hexch + ((size_t)((tau & 1) * 2 + dir) * 16) * 1024;
            bf8 Af[8];
#pragma unroll
            for (int k = 0; k < 8; k++) {
                const int sA = k * 2 + (quad >> 1);          // slice holding k-cols [k*32+quad*8, +8)
                Af[k] = load_sc1_b128(hb + (size_t)sA * 1024 + (w * 16 + l16) * 16 + (quad & 1) * 8);
            }
            asm volatile("s_waitcnt vmcnt(0)" ::: "memory");
            __builtin_amdgcn_sched_barrier(0);   // rule 18: keep MFMAs below the asm waitcnt

            f32x4 acc[4];
            const f32x4 zero = {0.f, 0.f, 0.f, 0.f};
#pragma unroll
            for (int g = 0; g < 4; g++) acc[g] = zero;
#pragma unroll
            for (int k = 0; k < 8; k++)
#pragma unroll
                for (int g = 0; g < 4; g++)
                    acc[g] = __builtin_amdgcn_mfma_f32_16x16x32_bf16(Af[k], Bf[g][k], acc[g], 0, 0, 0);

            // Gates; lane holds i,f,g,o for (b = w*16+quad*4+r, j = s*16+l16).
            float hv[4];
#pragma unroll
            for (int r = 0; r < 4; r++) {
                union { unsigned int u; float f; } cv0, cv1, cv2, cv3;
                cv0.u = (unsigned int)xpu[0][r] << 16;
                cv1.u = (unsigned int)xpu[1][r] << 16;
                cv2.u = (unsigned int)xpu[2][r] << 16;
                cv3.u = (unsigned int)xpu[3][r] << 16;
                const float ig = sigm(acc[0][r] + cv0.f);
                const float fg = sigm(acc[1][r] + cv1.f);
                const float gg = tanh_(acc[2][r] + cv2.f);
                const float og = sigm(acc[3][r] + cv3.f);
                c[r] = fg * c[r] + ig * gg;
                hv[r] = og * tanh_(c[r]);
                const int b = w * 16 + quad * 4 + r;
                ((__hip_bfloat16*)hstage)[b * 16 + l16] = __float2bfloat16(hv[r]);
            }
            __syncthreads();   // hstage complete

            // Publish h_{tau+1}: sc1 write-through dwordx2 per thread into the LLC.
            {
                unsigned int* dst = hexchU + ((size_t)(((tau + 1) & 1) * 2 + dir) * 16 + s) * 512;
                store_sc1_b64(&dst[2 * tid], hstage[2 * tid], hstage[2 * tid + 1]);
            }
            asm volatile("s_waitcnt vmcnt(0)" ::: "memory");   // per-wave drain: data in LLC
            __syncthreads();                                    // all waves drained
            if (tid == 0)
                store_sc1_b32(&flags[(dir * 16 + s) * 32], (unsigned int)(tau + 1));

            // Output stores off the critical path (drain overlaps next spin).
#pragma unroll
            for (int r = 0; r < 4; r++) {
                const int b = w * 16 + quad * 4 + r;
                __builtin_nontemporal_store(hv[r], &out[((size_t)b * T_SEQ + t) * 512 + dir * 256 + s * 16 + l16]);
            }
        }
    } else {
        // ================= XPROJ body (stage-remapped, sc1 stores, counter signal) =================
        const int xp4 = blockIdx.x - 32;          // [0, 8192)
        const int st  = xp4 >> 10;                // stage 0..7
        const int r1  = xp4 & 1023;
        const int dir = r1 >> 9;
        const int r2  = r1 & 511;
        const int yb  = r2 >> 6;                  // n-tile 0..7
        const int bb  = r2 & 63;                  // batch 0..63
        const int chunk = dir ? (7 - st) : st;    // t-chunk this block produces
        const int m0 = bb * 1024 + chunk * 128;   // 128 contiguous m within batch bb
        const int n0 = yb * 128;

        const float* W  = dir ? WihB : WihF;
        const float* bi = dir ? bihB : bihF;
        const float* bh = dir ? bhhB : bhhF;
        __hip_bfloat16* Xp = dir ? XpB : XpF;

        short* As = (short*)smem;                 // 128 x 32
        short* Bs = (short*)(smem + 8192);        // 128 x 32

        const int w2   = tid >> 6;
        const int wr   = w2 >> 1, wc = w2 & 1;    // 2x2 wave grid, 64x64 per wave
        const int srow = tid >> 2;                // staging row within 64-row half
        const int scg  = tid & 3;                 // 8-col group

        f32x4 acc[4][4] = {};

        for (int kk = 0; kk < 512; kk += 32) {
            const float* pa0 = X + (size_t)(m0 + srow)      * 512 + kk + scg * 8;
            const float* pa1 = X + (size_t)(m0 + 64 + srow) * 512 + kk + scg * 8;
            const float* pb0 = W + (size_t)(n0 + srow)      * 512 + kk + scg * 8;
            const float* pb1 = W + (size_t)(n0 + 64 + srow) * 512 + kk + scg * 8;
            bf8 a0 = pack_bf8(*(const float4*)pa0, *(const float4*)(pa0 + 4));
            bf8 a1 = pack_bf8(*(const float4*)pa1, *(const float4*)(pa1 + 4));
            bf8 b0 = pack_bf8(*(const float4*)pb0, *(const float4*)(pb0 + 4));
            bf8 b1 = pack_bf8(*(const float4*)pb1, *(const float4*)(pb1 + 4));
            __syncthreads();  // previous iteration's LDS reads done
            *(bf8*)&As[(srow)      * 32 + scg * 8] = a0;
            *(bf8*)&As[(64 + srow) * 32 + scg * 8] = a1;
            *(bf8*)&Bs[(srow)      * 32 + scg * 8] = b0;
            *(bf8*)&Bs[(64 + srow) * 32 + scg * 8] = b1;
            __syncthreads();

            bf8 af[4], bfr[4];
#pragma unroll
            for (int mt = 0; mt < 4; mt++)
                af[mt] = *(const bf8*)&As[(wr * 64 + mt * 16 + l16) * 32 + quad * 8];
#pragma unroll
            for (int nt = 0; nt < 4; nt++)
                bfr[nt] = *(const bf8*)&Bs[(wc * 64 + nt * 16 + l16) * 32 + quad * 8];
#pragma unroll
            for (int mt = 0; mt < 4; mt++)
#pragma unroll
                for (int nt = 0; nt < 4; nt++)
                    acc[mt][nt] = __builtin_amdgcn_mfma_f32_16x16x32_bf16(af[mt], bfr[nt], acc[mt][nt], 0, 0, 0);
        }

        // Epilogue: sc1 write-through stores (visible at LLC), then drain + signal.
#pragma unroll
        for (int nt = 0; nt < 4; nt++) {
            const int n = n0 + wc * 64 + nt * 16 + l16;
            const float bias = bi[n] + bh[n];
#pragma unroll
            for (int mt = 0; mt < 4; mt++) {
#pragma unroll
                for (int r = 0; r < 4; r++) {
                    const int m = m0 + wr * 64 + mt * 16 + quad * 4 + r;   // C/D: row=quad*4+r, col=l16
                    const int b = m >> 10, t = m & 1023;                    // m = b*1024 + t
                    store_sc1_b16(&Xp[((size_t)t * 64 + b) * 1024 + n],
                                  (unsigned short)bf16s(acc[mt][nt][r] + bias));
                }
            }
        }
        asm volatile("s_waitcnt vmcnt(0)" ::: "memory");   // per-wave drain: Xp in LLC
        __syncthreads();                                    // all waves drained
        if (tid == 0) atomicAdd(&cnt[dir * 8 + chunk], 1);  // device-scope, lands at LLC
    }
}

extern "C" void kernel_launch(void* const* d_in, const int* in_sizes, int n_in,
                              void* d_out, int out_size, void* d_ws, size_t ws_size,
                              hipStream_t stream)
{
    const float* X    = (const float*)d_in[0];
    const float* WihF = (const float*)d_in[1];
    const float* WhhF = (const float*)d_in[2];
    const float* bihF = (const float*)d_in[3];
    const float* bhhF = (const float*)d_in[4];
    const float* WihB = (const float*)d_in[5];
    const float* WhhB = (const float*)d_in[6];
    const float* bihB = (const float*)d_in[7];
    const float* bhhB = (const float*)d_in[8];
    float* out = (float*)d_out;

    char* ws = (char*)d_ws;
    __hip_bfloat16* XpF   = (__hip_bfloat16*)ws;                           // 128 MB
    __hip_bfloat16* XpB   = (__hip_bfloat16*)(ws + 134217728);             // 128 MB
    __hip_bfloat16* hexch = (__hip_bfloat16*)(ws + 268435456);             // 128 KB
    int*            flags = (int*)(ws + 268435456 + 131072);               // 4 KB (128 B spacing)
    int*            cnt   = (int*)(ws + 268435456 + 131072 + 4096);        // 64 B

    // Zero h_0 buffers, flags (0 == "h_0 ready") and chunk counters each replay.
    const int initN = (131072 + 4096 + 64) / 4;
    init_kernel<<<(initN + 255) / 256, 256, 0, stream>>>((unsigned int*)(ws + 268435456), initN);

    // One fused dispatch: 32 rec WGs (dispatched first) + 8192 stage-ordered xproj WGs.
    fused_kernel<<<8224, 256, 0, stream>>>(X, WihF, bihF, bhhF, WihB, bihB, bhhB,
                                           WhhF, WhhB, XpF, XpB, hexch, flags, cnt, out);
}